// Round 2
// 375.898 us; speedup vs baseline: 1.2469x; 1.2469x over previous
//
#include <hip/hip_runtime.h>
#include <math.h>

// ---- types ----------------------------------------------------------------
typedef __attribute__((ext_vector_type(8))) __bf16 bf16x8;   // MFMA A/B frag (4 VGPR)
typedef __attribute__((ext_vector_type(8))) short  short8;   // raw 16B store
typedef __attribute__((ext_vector_type(4))) unsigned short ushort4v;
typedef __attribute__((ext_vector_type(4))) float  floatx4;  // MFMA C/D frag

typedef __attribute__((address_space(1))) unsigned int as1_u32;
typedef __attribute__((address_space(3))) unsigned int as3_u32;

// async global->LDS, 16B per lane, dest = uniform base + lane*16
__device__ __forceinline__ void async_copy16(const void* g, void* l) {
  __builtin_amdgcn_global_load_lds((const as1_u32*)g, (as3_u32*)l, 16, 0, 0);
}

__device__ __forceinline__ unsigned short f2bf(float f) {  // RNE float->bf16 bits
  union { float f; unsigned u; } v; v.f = f;
  unsigned r = v.u + 0x7fffu + ((v.u >> 16) & 1u);
  return (unsigned short)(r >> 16);
}

__device__ __forceinline__ floatx4 mfma_bf16(bf16x8 a, bf16x8 b, floatx4 c) {
  return __builtin_amdgcn_mfma_f32_16x16x32_bf16(a, b, c, 0, 0, 0);
}

__device__ __forceinline__ bf16x8 lds_frag(const unsigned short* p) {
  return *(const bf16x8*)(const void*)p;  // ds_read_b128
}

// ---- prep: all four f32->bf16 conversions in ONE launch --------------------
__global__ __launch_bounds__(256)
void prep(const float* __restrict__ x,  const float* __restrict__ wq,
          const float* __restrict__ wk, const float* __restrict__ wv,
          unsigned short* __restrict__ Xb, unsigned short* __restrict__ Wqb,
          unsigned short* __restrict__ Wkb, unsigned short* __restrict__ Wvb) {
  const int i = blockIdx.x * 256 + threadIdx.x;
  const float* s; unsigned short* d; int off;
  if (i < 2097152)             { s = x;  d = Xb;  off = i; }
  else if (i < 2097152+65536)  { s = wq; d = Wqb; off = i - 2097152; }
  else if (i < 2097152+131072) { s = wk; d = Wkb; off = i - (2097152+65536); }
  else                         { s = wv; d = Wvb; off = i - (2097152+131072); }
  const float4 v = ((const float4*)s)[off];
  ushort4v o;
  o.x = f2bf(v.x); o.y = f2bf(v.y); o.z = f2bf(v.z); o.w = f2bf(v.w);
  *(ushort4v*)(void*)(d + (size_t)off * 4) = o;
}

// ---- fused QKV GEMM: unchanged (verified) ----------------------------------
__global__ __launch_bounds__(256, 2)
void gemm_qkv(const unsigned short* __restrict__ Xb,
              const unsigned short* __restrict__ Wqb,
              const unsigned short* __restrict__ Wkb,
              const unsigned short* __restrict__ Wvb,
              unsigned short* __restrict__ Q,
              unsigned short* __restrict__ K,
              unsigned short* __restrict__ Vt) {
  const int gid = blockIdx.x;
  const unsigned short *A, *B; unsigned short* C;
  int m0, n0, N;
  if (gid < 512) {                        // Q = Xb · Wq^T
    A = Xb; B = Wqb; C = Q; N = 512;
    m0 = (gid & 127) * 128; n0 = (gid >> 7) * 128;
  } else if (gid < 1024) {                // K = Xb · Wk^T
    A = Xb; B = Wkb; C = K; N = 512;
    m0 = ((gid - 512) & 127) * 128; n0 = ((gid - 512) >> 7) * 128;
  } else {                                // V^T = Wv · Xb^T  (M=512, N=16384)
    A = Wvb; B = Xb; C = Vt; N = 16384;
    m0 = ((gid - 1024) & 3) * 128; n0 = ((gid - 1024) >> 2) * 128;
  }

  __shared__ unsigned short As[128 * 64];
  __shared__ unsigned short Bs[128 * 64];
  const int tid = threadIdx.x;
  const int w = tid >> 6, lane = tid & 63;
  const int quad = lane >> 4, l15 = lane & 15;
  const int wm = w >> 1, wn = w & 1;
  const int row_l = lane >> 3;
  const int chk   = lane & 7;
  const int s_chk = chk ^ row_l;          // swizzled SOURCE chunk

  floatx4 acc[16];
#pragma unroll
  for (int i = 0; i < 16; i++) acc[i] = (floatx4){0.f, 0.f, 0.f, 0.f};

  for (int kt = 0; kt < 8; kt++) {
    __syncthreads();
#pragma unroll
    for (int i = 0; i < 4; i++) {
      const int c = w * 4 + i;
      const int row = c * 8 + row_l;
      async_copy16(A + (size_t)(m0 + row) * 512 + kt * 64 + s_chk * 8, &As[c * 512]);
      async_copy16(B + (size_t)(n0 + row) * 512 + kt * 64 + s_chk * 8, &Bs[c * 512]);
    }
    __syncthreads();
#pragma unroll
    for (int kc = 0; kc < 2; kc++) {
      bf16x8 af[4], bfv[4];
#pragma unroll
      for (int i = 0; i < 4; i++) {
        const int pc = ((kc * 4 + quad) ^ (l15 & 7)) * 8;
        af[i]  = lds_frag(&As[(wm * 64 + i * 16 + l15) * 64 + pc]);
        bfv[i] = lds_frag(&Bs[(wn * 64 + i * 16 + l15) * 64 + pc]);
      }
#pragma unroll
      for (int mi = 0; mi < 4; mi++)
#pragma unroll
        for (int ni = 0; ni < 4; ni++)
          acc[mi * 4 + ni] = mfma_bf16(af[mi], bfv[ni], acc[mi * 4 + ni]);
    }
  }
#pragma unroll
  for (int mi = 0; mi < 4; mi++)
#pragma unroll
    for (int ni = 0; ni < 4; ni++)
#pragma unroll
      for (int r = 0; r < 4; r++) {
        const int row = m0 + wm * 64 + mi * 16 + quad * 4 + r;
        const int col = n0 + wn * 64 + ni * 16 + l15;
        C[(size_t)row * N + col] = f2bf(acc[mi * 4 + ni][r]);
      }
}

// ---- fused attention: 8-wave / QBLK=64 / full-tile LDS / 4 barriers per step
// Round-2 bisect: round-1's cross-barrier DMA pipelining failed correctness
// with a stale-tile error signature (4.5e-3 ~ one tile's p-mass). This round
// keeps the geometry but uses the GEMM-VERIFIED transport pattern strictly:
//   B1 -> issue K+V -> B2 (vmcnt drain) -> compute. No DMA in flight during
// any compute phase; no cross-iteration prefetch. If this passes, re-add
// overlap incrementally next round.
#define SCALE 0.044194173824159216f  // 1/sqrt(512)

__global__ __launch_bounds__(512, 2)
void attn_kernel(const unsigned short* __restrict__ Qg,
                 const unsigned short* __restrict__ Kg,
                 const unsigned short* __restrict__ Vt,   // [512][16384] = V^T
                 float* __restrict__ O) {                 // f32 output
  __shared__ unsigned short Ks[64 * 512];   // 64 KB: 64 keys x 512 feats (swizzled)
  __shared__ unsigned short Vs[512 * 64];   // 64 KB: 512 d x 64 keys (swizzled)
  __shared__ float Sx[64][65];              // 16.6 KB
  __shared__ unsigned short Pb[64 * 72];    //  9.2 KB
  __shared__ float m_row[64], l_row[64], a_row[64];

  const int tid = threadIdx.x;
  const int w = tid >> 6, lane = tid & 63;
  const int quad = lane >> 4, l15 = lane & 15;
  const int wq = w >> 1, wd = w & 1;        // wq 0..3: q-sixteenth, wd: key/d half

  // XCD-contiguous swizzle: each XCD gets 32 consecutive logical blocks
  const int g0 = blockIdx.x;
  const int g  = (g0 & 7) * 32 + (g0 >> 3);   // 256 blocks, bijective
  const int b  = g >> 6;
  const int q0 = (g & 63) * 64;

  if (tid < 64) { m_row[tid] = -3.0e38f; l_row[tid] = 0.f; }

  // Q A-fragments in registers: 16 q-rows x 512 feats per wave (64 VGPR)
  bf16x8 qf[16];
  {
    const unsigned short* qrow = Qg + (size_t)(b * 4096 + q0 + wq * 16 + l15) * 512;
#pragma unroll
    for (int i = 0; i < 16; i++)
      qf[i] = *(const bf16x8*)(const void*)(qrow + i * 32 + quad * 8);
  }

  floatx4 oacc[16];   // 16 q x 256 d per wave
#pragma unroll
  for (int i = 0; i < 16; i++) oacc[i] = (floatx4){0.f, 0.f, 0.f, 0.f};

  const unsigned short* kb0 = Kg + (size_t)b * 4096 * 512;
  const unsigned short* vb0 = Vt + (size_t)b * 4096;
  const int v_d = lane >> 3, v_schk = (lane & 7) ^ v_d;

  // K tile stage: wave w, issue u: row = w*8+u (row&7 == u). LDS dest linear;
  // phys chunk p=lane holds logical chunk lane^u -> pre-swizzled global source.
  auto issue_K = [&](int kt_) {
#pragma unroll
    for (int u = 0; u < 8; u++) {
      const int row = w * 8 + u;
      async_copy16(kb0 + ((size_t)kt_ * 64 + row) * 512 + (lane ^ u) * 8,
                   &Ks[row * 512]);
    }
  };
  // V tile stage: wave w, issue u: d = w*64+u*8+(lane>>3); phys chunk (lane&7)
  // holds logical chunk (lane&7)^(d&7) = v_schk source chunk.
  auto issue_V = [&](int kt_) {
#pragma unroll
    for (int u = 0; u < 8; u++) {
      const int d = w * 64 + u * 8 + v_d;
      async_copy16(vb0 + (size_t)kt_ * 64 + (size_t)d * 16384 + v_schk * 8,
                   &Vs[(w * 64 + u * 8) * 64]);
    }
  };

  const int srow = tid >> 3, sg = tid & 7;

  for (int kt = 0; kt < 64; kt++) {
    __syncthreads();        // B1: all reads of previous K/V tiles complete
    issue_K(kt);
    issue_V(kt);
    __syncthreads();        // B2: vmcnt(0) drain -> Ks(kt), Vs(kt) resident

    // ---- phase 1: S(64q x 64k) = Q K^T, full D=512, 32 MFMA/wave
    floatx4 sacc[2];
    sacc[0] = (floatx4){0.f, 0.f, 0.f, 0.f};
    sacc[1] = (floatx4){0.f, 0.f, 0.f, 0.f};
#pragma unroll
    for (int kk = 0; kk < 16; kk++) {
#pragma unroll
      for (int s = 0; s < 2; s++) {
        const int krow = wd * 32 + s * 16 + l15;
        bf16x8 bfr = lds_frag(&Ks[krow * 512 + (((kk * 4 + quad) ^ (l15 & 7)) * 8)]);
        sacc[s] = mfma_bf16(qf[kk], bfr, sacc[s]);
      }
    }
#pragma unroll
    for (int s = 0; s < 2; s++)
#pragma unroll
      for (int r = 0; r < 4; r++)
        Sx[wq * 16 + quad * 4 + r][wd * 32 + s * 16 + l15] = sacc[s][r] * SCALE;
    __syncthreads();        // B3: Sx visible

    // ---- phase 2: online softmax (fp32), 8 lanes per q-row
    {
      float vals[8];
      float tmax = -3.0e38f;
#pragma unroll
      for (int j = 0; j < 8; j++) {
        float xv = Sx[srow][sg * 8 + j];
        xv = fminf(fmaxf(xv, -1.0e4f), 1.0e4f);
        vals[j] = xv;
        tmax = fmaxf(tmax, xv);
      }
      tmax = fmaxf(tmax, __shfl_xor(tmax, 1));
      tmax = fmaxf(tmax, __shfl_xor(tmax, 2));
      tmax = fmaxf(tmax, __shfl_xor(tmax, 4));
      const float m_old = m_row[srow];
      const float m_new = fmaxf(m_old, tmax);
      const float alpha = __expf(m_old - m_new);
      float lsum = 0.f;
      short8 pvec;
#pragma unroll
      for (int j = 0; j < 8; j++) {
        const float p = __expf(vals[j] - m_new);
        lsum += p;
        pvec[j] = (short)f2bf(p);
      }
      lsum += __shfl_xor(lsum, 1);
      lsum += __shfl_xor(lsum, 2);
      lsum += __shfl_xor(lsum, 4);
      *(short8*)(void*)&Pb[srow * 72 + sg * 8] = pvec;
      if (sg == 0) {
        m_row[srow] = m_new;
        l_row[srow] = l_row[srow] * alpha + lsum;
        a_row[srow] = alpha;
      }
    }
    __syncthreads();        // B4: Pb, a_row visible

    // ---- phase 3: O = O*alpha + P V, 32 MFMA/wave
    float ar[4];
#pragma unroll
    for (int r = 0; r < 4; r++) ar[r] = a_row[wq * 16 + quad * 4 + r];
#pragma unroll
    for (int j = 0; j < 16; j++)
#pragma unroll
      for (int r = 0; r < 4; r++) oacc[j][r] *= ar[r];
    bf16x8 pf[2];
#pragma unroll
    for (int kc = 0; kc < 2; kc++)
      pf[kc] = lds_frag(&Pb[(wq * 16 + l15) * 72 + kc * 32 + quad * 8]);
#pragma unroll
    for (int j = 0; j < 16; j++) {
      const int vrow = wd * 256 + j * 16 + l15;
#pragma unroll
      for (int kc = 0; kc < 2; kc++) {
        bf16x8 bfr = lds_frag(&Vs[vrow * 64 + (((kc * 4 + quad) ^ (l15 & 7)) * 8)]);
        oacc[j] = mfma_bf16(pf[kc], bfr, oacc[j]);
      }
    }
  }

  // ---- epilogue: O / l, f32 store
  __syncthreads();
  float invl[4];
#pragma unroll
  for (int r = 0; r < 4; r++) invl[r] = 1.0f / l_row[wq * 16 + quad * 4 + r];
#pragma unroll
  for (int j = 0; j < 16; j++) {
#pragma unroll
    for (int r = 0; r < 4; r++) {
      const int row = b * 4096 + q0 + wq * 16 + quad * 4 + r;
      O[(size_t)row * 512 + wd * 256 + j * 16 + l15] = oacc[j][r] * invl[r];
    }
  }
}

// ---- launch ---------------------------------------------------------------
extern "C" void kernel_launch(void* const* d_in, const int* in_sizes, int n_in,
                              void* d_out, int out_size, void* d_ws, size_t ws_size,
                              hipStream_t stream) {
  const float* x   = (const float*)d_in[0];
  const float* wqf = (const float*)d_in[1];
  const float* wkf = (const float*)d_in[2];
  const float* wvf = (const float*)d_in[3];

  unsigned short* Xb  = (unsigned short*)d_out;        // 16384 x 512 bf16 (dead before attn)
  unsigned short* Wqb = (unsigned short*)d_ws;         // 512 x 512
  unsigned short* Wkb = Wqb + (size_t)512 * 512;
  unsigned short* Wvb = Wkb + (size_t)512 * 512;
  unsigned short* Q   = Wvb + (size_t)512 * 512;       // 16384 x 512
  unsigned short* K   = Q + (size_t)16384 * 512;       // 16384 x 512
  unsigned short* Vt  = K + (size_t)16384 * 512;       // 512 x 16384 (V^T)

  prep<<<dim3(8960), 256, 0, stream>>>(x, wqf, wkf, wvf, Xb, Wqb, Wkb, Wvb);
  gemm_qkv<<<dim3(1536), 256, 0, stream>>>(Xb, Wqb, Wkb, Wvb, Q, K, Vt);
  attn_kernel<<<dim3(256), 512, 0, stream>>>(Q, K, Vt, (float*)d_out);
}

// Round 4
// 350.152 us; speedup vs baseline: 1.3386x; 1.0735x over previous
//
#include <hip/hip_runtime.h>
#include <math.h>

// ---- types ----------------------------------------------------------------
typedef __attribute__((ext_vector_type(8))) __bf16 bf16x8;   // MFMA A/B frag (4 VGPR)
typedef __attribute__((ext_vector_type(8))) short  short8;   // raw 16B store
typedef __attribute__((ext_vector_type(4))) unsigned short ushort4v;
typedef __attribute__((ext_vector_type(4))) float  floatx4;  // MFMA C/D frag

typedef __attribute__((address_space(1))) unsigned int as1_u32;
typedef __attribute__((address_space(3))) unsigned int as3_u32;

// async global->LDS, 16B per lane, dest = uniform base + lane*16
__device__ __forceinline__ void async_copy16(const void* g, void* l) {
  __builtin_amdgcn_global_load_lds((const as1_u32*)g, (as3_u32*)l, 16, 0, 0);
}

__device__ __forceinline__ unsigned short f2bf(float f) {  // RNE float->bf16 bits
  union { float f; unsigned u; } v; v.f = f;
  unsigned r = v.u + 0x7fffu + ((v.u >> 16) & 1u);
  return (unsigned short)(r >> 16);
}

__device__ __forceinline__ floatx4 mfma_bf16(bf16x8 a, bf16x8 b, floatx4 c) {
  return __builtin_amdgcn_mfma_f32_16x16x32_bf16(a, b, c, 0, 0, 0);
}

__device__ __forceinline__ bf16x8 lds_frag(const unsigned short* p) {
  return *(const bf16x8*)(const void*)p;  // ds_read_b128
}

// ---- prep: all four f32->bf16 conversions in ONE launch --------------------
__global__ __launch_bounds__(256)
void prep(const float* __restrict__ x,  const float* __restrict__ wq,
          const float* __restrict__ wk, const float* __restrict__ wv,
          unsigned short* __restrict__ Xb, unsigned short* __restrict__ Wqb,
          unsigned short* __restrict__ Wkb, unsigned short* __restrict__ Wvb) {
  const int i = blockIdx.x * 256 + threadIdx.x;
  const float* s; unsigned short* d; int off;
  if (i < 2097152)             { s = x;  d = Xb;  off = i; }
  else if (i < 2097152+65536)  { s = wq; d = Wqb; off = i - 2097152; }
  else if (i < 2097152+131072) { s = wk; d = Wkb; off = i - (2097152+65536); }
  else                         { s = wv; d = Wvb; off = i - (2097152+131072); }
  const float4 v = ((const float4*)s)[off];
  ushort4v o;
  o.x = f2bf(v.x); o.y = f2bf(v.y); o.z = f2bf(v.z); o.w = f2bf(v.w);
  *(ushort4v*)(void*)(d + (size_t)off * 4) = o;
}

// ---- fused QKV GEMM: unchanged (verified) ----------------------------------
__global__ __launch_bounds__(256, 2)
void gemm_qkv(const unsigned short* __restrict__ Xb,
              const unsigned short* __restrict__ Wqb,
              const unsigned short* __restrict__ Wkb,
              const unsigned short* __restrict__ Wvb,
              unsigned short* __restrict__ Q,
              unsigned short* __restrict__ K,
              unsigned short* __restrict__ Vt) {
  const int gid = blockIdx.x;
  const unsigned short *A, *B; unsigned short* C;
  int m0, n0, N;
  if (gid < 512) {                        // Q = Xb · Wq^T
    A = Xb; B = Wqb; C = Q; N = 512;
    m0 = (gid & 127) * 128; n0 = (gid >> 7) * 128;
  } else if (gid < 1024) {                // K = Xb · Wk^T
    A = Xb; B = Wkb; C = K; N = 512;
    m0 = ((gid - 512) & 127) * 128; n0 = ((gid - 512) >> 7) * 128;
  } else {                                // V^T = Wv · Xb^T  (M=512, N=16384)
    A = Wvb; B = Xb; C = Vt; N = 16384;
    m0 = ((gid - 1024) & 3) * 128; n0 = ((gid - 1024) >> 2) * 128;
  }

  __shared__ unsigned short As[128 * 64];
  __shared__ unsigned short Bs[128 * 64];
  const int tid = threadIdx.x;
  const int w = tid >> 6, lane = tid & 63;
  const int quad = lane >> 4, l15 = lane & 15;
  const int wm = w >> 1, wn = w & 1;
  const int row_l = lane >> 3;
  const int chk   = lane & 7;
  const int s_chk = chk ^ row_l;          // swizzled SOURCE chunk

  floatx4 acc[16];
#pragma unroll
  for (int i = 0; i < 16; i++) acc[i] = (floatx4){0.f, 0.f, 0.f, 0.f};

  for (int kt = 0; kt < 8; kt++) {
    __syncthreads();
#pragma unroll
    for (int i = 0; i < 4; i++) {
      const int c = w * 4 + i;
      const int row = c * 8 + row_l;
      async_copy16(A + (size_t)(m0 + row) * 512 + kt * 64 + s_chk * 8, &As[c * 512]);
      async_copy16(B + (size_t)(n0 + row) * 512 + kt * 64 + s_chk * 8, &Bs[c * 512]);
    }
    __syncthreads();
#pragma unroll
    for (int kc = 0; kc < 2; kc++) {
      bf16x8 af[4], bfv[4];
#pragma unroll
      for (int i = 0; i < 4; i++) {
        const int pc = ((kc * 4 + quad) ^ (l15 & 7)) * 8;
        af[i]  = lds_frag(&As[(wm * 64 + i * 16 + l15) * 64 + pc]);
        bfv[i] = lds_frag(&Bs[(wn * 64 + i * 16 + l15) * 64 + pc]);
      }
#pragma unroll
      for (int mi = 0; mi < 4; mi++)
#pragma unroll
        for (int ni = 0; ni < 4; ni++)
          acc[mi * 4 + ni] = mfma_bf16(af[mi], bfv[ni], acc[mi * 4 + ni]);
    }
  }
#pragma unroll
  for (int mi = 0; mi < 4; mi++)
#pragma unroll
    for (int ni = 0; ni < 4; ni++)
#pragma unroll
      for (int r = 0; r < 4; r++) {
        const int row = m0 + wm * 64 + mi * 16 + quad * 4 + r;
        const int col = n0 + wn * 64 + ni * 16 + l15;
        C[(size_t)row * N + col] = f2bf(acc[mi * 4 + ni][r]);
      }
}

// ---- fused attention: 8-wave / QBLK=64 / full-tile LDS / pipelined DMA -----
// Round-3 (resubmit; round-3 bench was an infra timeout, kernel never ran):
// R2 (conservative, verified) + DMA overlap with EXPLICIT drains.
// R1 raced because it relied on the compiler auto-draining vmcnt at
// __syncthreads when the DMA->read dependency spans regions/back-edges.
// Here every tile is published by: asm s_waitcnt vmcnt(0) + sched_barrier
// + __syncthreads. Each wave provably drains its own DMAs before arrival;
// barrier exit => all waves' writes resident. Buffer-death argument:
//   Vs(kt-1) last read in phase 3 (before B1)  -> issue_V(kt) after B1
//   Ks(kt)   last read in phase 1 (before B2)  -> issue_K(kt+1) after B4
// V flies under QK^T+softmax; K flies under PV.
#define SCALE 0.044194173824159216f  // 1/sqrt(512)

__global__ __launch_bounds__(512, 2)
void attn_kernel(const unsigned short* __restrict__ Qg,
                 const unsigned short* __restrict__ Kg,
                 const unsigned short* __restrict__ Vt,   // [512][16384] = V^T
                 float* __restrict__ O) {                 // f32 output
  __shared__ unsigned short Ks[64 * 512];   // 64 KB: 64 keys x 512 feats (swizzled)
  __shared__ unsigned short Vs[512 * 64];   // 64 KB: 512 d x 64 keys (swizzled)
  __shared__ float Sx[64][65];              // 16.6 KB
  __shared__ unsigned short Pb[64 * 72];    //  9.2 KB
  __shared__ float m_row[64], l_row[64], a_row[64];

  const int tid = threadIdx.x;
  const int w = tid >> 6, lane = tid & 63;
  const int quad = lane >> 4, l15 = lane & 15;
  const int wq = w >> 1, wd = w & 1;        // wq 0..3: q-sixteenth, wd: key/d half

  // XCD-contiguous swizzle: each XCD gets 32 consecutive logical blocks
  const int g0 = blockIdx.x;
  const int g  = (g0 & 7) * 32 + (g0 >> 3);   // 256 blocks, bijective
  const int b  = g >> 6;
  const int q0 = (g & 63) * 64;

  if (tid < 64) { m_row[tid] = -3.0e38f; l_row[tid] = 0.f; }

  // Q A-fragments in registers: 16 q-rows x 512 feats per wave (64 VGPR)
  bf16x8 qf[16];
  {
    const unsigned short* qrow = Qg + (size_t)(b * 4096 + q0 + wq * 16 + l15) * 512;
#pragma unroll
    for (int i = 0; i < 16; i++)
      qf[i] = *(const bf16x8*)(const void*)(qrow + i * 32 + quad * 8);
  }

  floatx4 oacc[16];   // 16 q x 256 d per wave
#pragma unroll
  for (int i = 0; i < 16; i++) oacc[i] = (floatx4){0.f, 0.f, 0.f, 0.f};

  const unsigned short* kb0 = Kg + (size_t)b * 4096 * 512;
  const unsigned short* vb0 = Vt + (size_t)b * 4096;
  const int v_d = lane >> 3, v_schk = (lane & 7) ^ v_d;

  // K tile stage: wave w, issue u: row = w*8+u (row&7 == u). LDS dest linear;
  // phys chunk p=lane holds logical chunk lane^u -> pre-swizzled global source.
  auto issue_K = [&](int kt_) {
#pragma unroll
    for (int u = 0; u < 8; u++) {
      const int row = w * 8 + u;
      async_copy16(kb0 + ((size_t)kt_ * 64 + row) * 512 + (lane ^ u) * 8,
                   &Ks[row * 512]);
    }
  };
  // V tile stage: wave w, issue u: d = w*64+u*8+(lane>>3); phys chunk (lane&7)
  // holds logical chunk (lane&7)^(d&7) = v_schk source chunk.
  auto issue_V = [&](int kt_) {
#pragma unroll
    for (int u = 0; u < 8; u++) {
      const int d = w * 64 + u * 8 + v_d;
      async_copy16(vb0 + (size_t)kt_ * 64 + (size_t)d * 16384 + v_schk * 8,
                   &Vs[(w * 64 + u * 8) * 64]);
    }
  };

  const int srow = tid >> 3, sg = tid & 7;

  issue_K(0);   // prologue: K(0) in flight; published at B1 of kt=0

  for (int kt = 0; kt < 64; kt++) {
    // B1: publish Ks(kt). Explicit per-wave drain makes cross-wave rows safe.
    asm volatile("s_waitcnt vmcnt(0)" ::: "memory");
    __builtin_amdgcn_sched_barrier(0);
    __syncthreads();
    issue_V(kt);            // Vs dead since B1; flies under phase 1 + softmax

    // ---- phase 1: S(64q x 64k) = Q K^T, full D=512, 32 MFMA/wave
    floatx4 sacc[2];
    sacc[0] = (floatx4){0.f, 0.f, 0.f, 0.f};
    sacc[1] = (floatx4){0.f, 0.f, 0.f, 0.f};
#pragma unroll
    for (int kk = 0; kk < 16; kk++) {
#pragma unroll
      for (int s = 0; s < 2; s++) {
        const int krow = wd * 32 + s * 16 + l15;
        bf16x8 bfr = lds_frag(&Ks[krow * 512 + (((kk * 4 + quad) ^ (l15 & 7)) * 8)]);
        sacc[s] = mfma_bf16(qf[kk], bfr, sacc[s]);
      }
    }
#pragma unroll
    for (int s = 0; s < 2; s++)
#pragma unroll
      for (int r = 0; r < 4; r++)
        Sx[wq * 16 + quad * 4 + r][wd * 32 + s * 16 + l15] = sacc[s][r] * SCALE;
    __syncthreads();        // B2: Sx visible (V DMA still in flight - ok)

    // ---- phase 2: online softmax (fp32), 8 lanes per q-row
    {
      float vals[8];
      float tmax = -3.0e38f;
#pragma unroll
      for (int j = 0; j < 8; j++) {
        float xv = Sx[srow][sg * 8 + j];
        xv = fminf(fmaxf(xv, -1.0e4f), 1.0e4f);
        vals[j] = xv;
        tmax = fmaxf(tmax, xv);
      }
      tmax = fmaxf(tmax, __shfl_xor(tmax, 1));
      tmax = fmaxf(tmax, __shfl_xor(tmax, 2));
      tmax = fmaxf(tmax, __shfl_xor(tmax, 4));
      const float m_old = m_row[srow];
      const float m_new = fmaxf(m_old, tmax);
      const float alpha = __expf(m_old - m_new);
      float lsum = 0.f;
      short8 pvec;
#pragma unroll
      for (int j = 0; j < 8; j++) {
        const float p = __expf(vals[j] - m_new);
        lsum += p;
        pvec[j] = (short)f2bf(p);
      }
      lsum += __shfl_xor(lsum, 1);
      lsum += __shfl_xor(lsum, 2);
      lsum += __shfl_xor(lsum, 4);
      *(short8*)(void*)&Pb[srow * 72 + sg * 8] = pvec;
      if (sg == 0) {
        m_row[srow] = m_new;
        l_row[srow] = l_row[srow] * alpha + lsum;
        a_row[srow] = alpha;
      }
    }
    __syncthreads();        // B3: Pb, a_row visible (V DMA still in flight - ok)

    // ---- hoisted pre-PV work (touches neither Vs nor DMA): P frags + rescale
    float ar[4];
#pragma unroll
    for (int r = 0; r < 4; r++) ar[r] = a_row[wq * 16 + quad * 4 + r];
#pragma unroll
    for (int j = 0; j < 16; j++)
#pragma unroll
      for (int r = 0; r < 4; r++) oacc[j][r] *= ar[r];
    bf16x8 pf[2];
#pragma unroll
    for (int kc = 0; kc < 2; kc++)
      pf[kc] = lds_frag(&Pb[(wq * 16 + l15) * 72 + kc * 32 + quad * 8]);

    // B4: publish Vs(kt).
    asm volatile("s_waitcnt vmcnt(0)" ::: "memory");
    __builtin_amdgcn_sched_barrier(0);
    __syncthreads();
    if (kt < 63) issue_K(kt + 1);   // Ks dead since B2; flies under phase 3

    // ---- phase 3: O += P V, 32 MFMA/wave
#pragma unroll
    for (int j = 0; j < 16; j++) {
      const int vrow = wd * 256 + j * 16 + l15;
#pragma unroll
      for (int kc = 0; kc < 2; kc++) {
        bf16x8 bfr = lds_frag(&Vs[vrow * 64 + (((kc * 4 + quad) ^ (l15 & 7)) * 8)]);
        oacc[j] = mfma_bf16(pf[kc], bfr, oacc[j]);
      }
    }
  }

  // ---- epilogue: O / l, f32 store
  __syncthreads();
  float invl[4];
#pragma unroll
  for (int r = 0; r < 4; r++) invl[r] = 1.0f / l_row[wq * 16 + quad * 4 + r];
#pragma unroll
  for (int j = 0; j < 16; j++) {
#pragma unroll
    for (int r = 0; r < 4; r++) {
      const int row = b * 4096 + q0 + wq * 16 + quad * 4 + r;
      O[(size_t)row * 512 + wd * 256 + j * 16 + l15] = oacc[j][r] * invl[r];
    }
  }
}

// ---- launch ---------------------------------------------------------------
extern "C" void kernel_launch(void* const* d_in, const int* in_sizes, int n_in,
                              void* d_out, int out_size, void* d_ws, size_t ws_size,
                              hipStream_t stream) {
  const float* x   = (const float*)d_in[0];
  const float* wqf = (const float*)d_in[1];
  const float* wkf = (const float*)d_in[2];
  const float* wvf = (const float*)d_in[3];

  unsigned short* Xb  = (unsigned short*)d_out;        // 16384 x 512 bf16 (dead before attn)
  unsigned short* Wqb = (unsigned short*)d_ws;         // 512 x 512
  unsigned short* Wkb = Wqb + (size_t)512 * 512;
  unsigned short* Wvb = Wkb + (size_t)512 * 512;
  unsigned short* Q   = Wvb + (size_t)512 * 512;       // 16384 x 512
  unsigned short* K   = Q + (size_t)16384 * 512;       // 16384 x 512
  unsigned short* Vt  = K + (size_t)16384 * 512;       // 512 x 16384 (V^T)

  prep<<<dim3(8960), 256, 0, stream>>>(x, wqf, wkf, wvf, Xb, Wqb, Wkb, Wvb);
  gemm_qkv<<<dim3(1536), 256, 0, stream>>>(Xb, Wqb, Wkb, Wvb, Q, K, Vt);
  attn_kernel<<<dim3(256), 512, 0, stream>>>(Q, K, Vt, (float*)d_out);
}